// Round 1
// baseline (274.326 us; speedup 1.0000x reference)
//
#include <hip/hip_runtime.h>
#include <hip/hip_bf16.h>

// Gathered skinny GEMM: out[b, r] = sum_d x[b,d] * w[indices[r], d]
//   x: [32][4096] f32, w: [11008][4096] f32, indices: [4403] i32,
//   out: [32][4403] f32
//
// R6: the 239us is 2x ~108.5us harness workspace-poison fills (688 MiB @ 83%
// HBM peak, not controllable) + ~22us of our kernels. Floor for our slice is
// ~13us (72 MB gathered-W HBM read). Changes vs R5:
//   - p0 fused into p1: x loaded as f32 (512 KB, L2-resident) and converted
//     to bf16 in-register. One less launch, no xb round-trip.
//   - p2 + 18 MB partial-buffer HBM traffic replaced by direct fp32 atomics
//     into out (563 KB, cache-resident; unsafeAtomicAdd = native
//     global_atomic_add_f32) after a hipMemsetAsync zero of out.
//   - padded rows (r >= REMAINED) masked per-element at the atomic.
// MFMA layout unchanged (16x16x32 bf16, per m89/m91/m120):
//   A = gathered W rows: lane(quad=l>>4, m=l&15) reads
//       W[idx[rt*16+m]][k0 + s*32 + quad*8 + 0..7] (32 B contiguous), cvt bf16.
//   B = x rows b=m and b=m+16, same k-slice, cvt bf16.
//   D: lane holds D[m'=quad*4+reg][n=lane&15] -> 4 consecutive r's for batch n.
// KSPLIT=16 -> 4416 waves (1104 blocks, ~4.3 blocks/CU), k-plane partials
// accumulated via atomics instead of a partial tensor.

#define D_MODEL   4096
#define REMAINED  4403
#define BATCH     32
#define KSPLIT    16
#define KCHUNK    (D_MODEL / KSPLIT)      // 256 floats
#define KSTEPS    (KCHUNK / 32)           // 8 MFMA k-steps per wave
#define RT16      ((REMAINED + 15) / 16)  // 276 r-tiles
#define BLOCK     256
#define GRID1     ((RT16 * KSPLIT) / 4)   // 4416 waves / 4 per block = 1104

typedef __attribute__((ext_vector_type(8))) short  short8;   // 8 bf16
typedef __attribute__((ext_vector_type(4))) float  floatx4;  // 4 fp32 acc

union ABFrag { short8 s8; __hip_bfloat162 h2[4]; };

__device__ __forceinline__ short8 cvt8(const float4 a, const float4 b) {
    ABFrag f;
    f.h2[0] = __float22bfloat162_rn(make_float2(a.x, a.y));
    f.h2[1] = __float22bfloat162_rn(make_float2(a.z, a.w));
    f.h2[2] = __float22bfloat162_rn(make_float2(b.x, b.y));
    f.h2[3] = __float22bfloat162_rn(make_float2(b.z, b.w));
    return f.s8;
}

__global__ __launch_bounds__(BLOCK) void p1_mfma(
    const float* __restrict__ w,
    const int*   __restrict__ idx,
    const float* __restrict__ x,
    float*       __restrict__ out)
{
    const int wid  = blockIdx.x * 4 + ((int)threadIdx.x >> 6);
    const int lane = (int)threadIdx.x & 63;
    const int quad = lane >> 4;
    const int m    = lane & 15;

    const int rt = wid % RT16;
    const int ks = wid / RT16;

    // gathered W row for this lane's A-fragment rows
    const int r   = rt * 16 + m;
    const int rc  = (r < REMAINED) ? r : (REMAINED - 1);  // padded rows: dup,
    const int row = idx[rc];                              // masked at the store

    // per step s: lane reads W[row][ks*KCHUNK + s*32 + quad*8 + 0..7]
    const float4* __restrict__ wp =
        (const float4*)(w + (size_t)row * D_MODEL + ks * KCHUNK) + quad * 2;

    // B operands: x[b][same k-slice] as f32 (L2-resident), b = m and m+16
    const float4* __restrict__ xp0 =
        (const float4*)(x + (size_t)m * D_MODEL + ks * KCHUNK) + quad * 2;
    const float4* __restrict__ xp1 =
        (const float4*)(x + (size_t)(m + 16) * D_MODEL + ks * KCHUNK) + quad * 2;

    floatx4 acc0 = {0.f, 0.f, 0.f, 0.f};
    floatx4 acc1 = {0.f, 0.f, 0.f, 0.f};

#pragma unroll
    for (int s = 0; s < KSTEPS; ++s) {
        const float4 w0 = wp[s * 8 + 0];
        const float4 w1 = wp[s * 8 + 1];
        const float4 a0 = xp0[s * 8 + 0];
        const float4 a1 = xp0[s * 8 + 1];
        const float4 b0 = xp1[s * 8 + 0];
        const float4 b1 = xp1[s * 8 + 1];

        const short8 af = cvt8(w0, w1);
        const short8 x0 = cvt8(a0, a1);
        const short8 x1 = cvt8(b0, b1);

        acc0 = __builtin_amdgcn_mfma_f32_16x16x32_bf16(af, x0, acc0, 0, 0, 0);
        acc1 = __builtin_amdgcn_mfma_f32_16x16x32_bf16(af, x1, acc1, 0, 0, 0);
    }

    // D[m'=quad*4+reg][n=lane&15]: lane holds 4 consecutive r's for batch n.
    // Accumulate k-planes directly into out via native f32 atomics.
    const int rbase = rt * 16 + quad * 4;
    float* o0 = out + (size_t)m * REMAINED + rbase;
    float* o1 = out + (size_t)(m + 16) * REMAINED + rbase;

#pragma unroll
    for (int j = 0; j < 4; ++j) {
        if (rbase + j < REMAINED) {
            unsafeAtomicAdd(o0 + j, acc0[j]);
            unsafeAtomicAdd(o1 + j, acc1[j]);
        }
    }
}

extern "C" void kernel_launch(void* const* d_in, const int* in_sizes, int n_in,
                              void* d_out, int out_size, void* d_ws, size_t ws_size,
                              hipStream_t stream) {
    const float* x   = (const float*)d_in[0];
    const float* w   = (const float*)d_in[1];
    const int*   idx = (const int*)d_in[2];
    float*       out = (float*)d_out;

    (void)d_ws; (void)ws_size;

    hipMemsetAsync(out, 0, (size_t)BATCH * REMAINED * sizeof(float), stream);
    p1_mfma<<<GRID1, BLOCK, 0, stream>>>(w, idx, x, out);
}

// Round 2
// 246.282 us; speedup vs baseline: 1.1139x; 1.1139x over previous
//
#include <hip/hip_runtime.h>
#include <hip/hip_bf16.h>

// Gathered skinny GEMM: out[b, r] = sum_d x[b,d] * w[indices[r], d]
//   x: [32][4096] f32, w: [11008][4096] f32, indices: [4403] i32,
//   out: [32][4403] f32
//
// R7: R6's regression (274us, +35 vs R5) was the atomic scheme: 2.26M
// device-scope f32 atomics with 16-way same-address contention (16 k-planes
// per output co-resident) serialize at the cross-XCD coherence point.
// Fix: reduce k-planes ON-CHIP.
//   - Block = 4 waves sharing one r-tile; rt = blockIdx%276, kh = blockIdx/276
//     (2 k-halves -> 552 blocks, 2.16/CU, good balance). Wave w owns the
//     contiguous 512-float K-chunk (kh*4+w)*512; KSTEPS=16.
//   - 4 waves' accumulators reduced via 8 KB LDS -> ONE atomic per output per
//     kh: 283K atomics (8x fewer than R6), 2-way contention, hidden under the
//     HBM stream. out zeroed by hipMemsetAsync (graph-legal).
//   - x loaded f32 from L2 (512 KB resident), cvt to bf16 in-register (keeps
//     R6's p0 fusion; ~144 MB L2 traffic @ 34 TB/s overlaps the HBM stream).
// Floor: ~72 MB gathered W @ 6.3 TB/s ~= 11.5us.
// MFMA layout unchanged (16x16x32 bf16, per m89/m91/m120):
//   A = gathered W rows: lane(quad=l>>4, m=l&15) reads
//       W[idx[rt*16+m]][k0 + s*32 + quad*8 + 0..7] (32 B contiguous), cvt bf16.
//   B = x rows b=m and b=m+16, same k-slice, cvt bf16.
//   D: lane holds D[r_local=quad*4+j][b=lane&15 (+16 for acc1)].

#define D_MODEL   4096
#define REMAINED  4403
#define BATCH     32
#define RT16      ((REMAINED + 15) / 16)  // 276 r-tiles
#define KHALF     2
#define KCHUNK    (D_MODEL / KHALF / 4)   // 512 floats per wave
#define KSTEPS    (KCHUNK / 32)           // 16 MFMA k-steps per wave
#define BLOCK     256
#define GRID1     (RT16 * KHALF)          // 552 blocks

typedef __attribute__((ext_vector_type(8))) short  short8;   // 8 bf16
typedef __attribute__((ext_vector_type(4))) float  floatx4;  // 4 fp32 acc

union ABFrag { short8 s8; __hip_bfloat162 h2[4]; };

__device__ __forceinline__ short8 cvt8(const float4 a, const float4 b) {
    ABFrag f;
    f.h2[0] = __float22bfloat162_rn(make_float2(a.x, a.y));
    f.h2[1] = __float22bfloat162_rn(make_float2(a.z, a.w));
    f.h2[2] = __float22bfloat162_rn(make_float2(b.x, b.y));
    f.h2[3] = __float22bfloat162_rn(make_float2(b.z, b.w));
    return f.s8;
}

__global__ __launch_bounds__(BLOCK) void p1_mfma(
    const float* __restrict__ w,
    const int*   __restrict__ idx,
    const float* __restrict__ x,
    float*       __restrict__ out)
{
    const int warp = (int)threadIdx.x >> 6;
    const int lane = (int)threadIdx.x & 63;
    const int quad = lane >> 4;
    const int m    = lane & 15;

    const int rt = (int)blockIdx.x % RT16;
    const int kh = (int)blockIdx.x / RT16;
    const int k0 = (kh * 4 + warp) * KCHUNK;   // this wave's K origin (floats)

    // gathered W row for this lane's A-fragment rows
    const int r   = rt * 16 + m;
    const int rc  = (r < REMAINED) ? r : (REMAINED - 1);  // padded rows: dup,
    const int row = idx[rc];                              // masked at the store

    // per step s: lane reads W[row][k0 + s*32 + quad*8 + 0..7]
    const float4* __restrict__ wp =
        (const float4*)(w + (size_t)row * D_MODEL + k0) + quad * 2;

    // B operands: x[b][same k-slice] as f32 (L2-resident), b = m and m+16
    const float4* __restrict__ xp0 =
        (const float4*)(x + (size_t)m * D_MODEL + k0) + quad * 2;
    const float4* __restrict__ xp1 =
        (const float4*)(x + (size_t)(m + 16) * D_MODEL + k0) + quad * 2;

    floatx4 acc0 = {0.f, 0.f, 0.f, 0.f};
    floatx4 acc1 = {0.f, 0.f, 0.f, 0.f};

#pragma unroll 4
    for (int s = 0; s < KSTEPS; ++s) {
        const float4 w0 = wp[s * 8 + 0];
        const float4 w1 = wp[s * 8 + 1];
        const float4 a0 = xp0[s * 8 + 0];
        const float4 a1 = xp0[s * 8 + 1];
        const float4 b0 = xp1[s * 8 + 0];
        const float4 b1 = xp1[s * 8 + 1];

        const short8 af = cvt8(w0, w1);
        const short8 x0 = cvt8(a0, a1);
        const short8 x1 = cvt8(b0, b1);

        acc0 = __builtin_amdgcn_mfma_f32_16x16x32_bf16(af, x0, acc0, 0, 0, 0);
        acc1 = __builtin_amdgcn_mfma_f32_16x16x32_bf16(af, x1, acc1, 0, 0, 0);
    }

    // ---- on-chip reduction of the 4 waves' k-partials --------------------
    // red[w][b*16 + r_local]; lane holds D[r_local=quad*4+j][b] for b=m, m+16
    __shared__ float red[4][BATCH * 16];

    float4* lp = (float4*)red[warp];
    lp[m * 4 + quad]        = make_float4(acc0[0], acc0[1], acc0[2], acc0[3]);
    lp[(m + 16) * 4 + quad] = make_float4(acc1[0], acc1[1], acc1[2], acc1[3]);
    __syncthreads();

    // 512 outputs / 256 threads = 2 each (same b, consecutive r)
    const int e  = (int)threadIdx.x * 2;
    const int b  = e >> 4;
    const int rl = e & 15;
    const int rr = rt * 16 + rl;

    const float s0 = (red[0][e] + red[1][e]) + (red[2][e] + red[3][e]);
    const float s1 = (red[0][e + 1] + red[1][e + 1]) + (red[2][e + 1] + red[3][e + 1]);

    float* o = out + (size_t)b * REMAINED;
    if (rr     < REMAINED) unsafeAtomicAdd(o + rr,     s0);
    if (rr + 1 < REMAINED) unsafeAtomicAdd(o + rr + 1, s1);
}

extern "C" void kernel_launch(void* const* d_in, const int* in_sizes, int n_in,
                              void* d_out, int out_size, void* d_ws, size_t ws_size,
                              hipStream_t stream) {
    const float* x   = (const float*)d_in[0];
    const float* w   = (const float*)d_in[1];
    const int*   idx = (const int*)d_in[2];
    float*       out = (float*)d_out;

    (void)d_ws; (void)ws_size;

    hipMemsetAsync(out, 0, (size_t)BATCH * REMAINED * sizeof(float), stream);
    p1_mfma<<<GRID1, BLOCK, 0, stream>>>(w, idx, x, out);
}